// Round 4
// baseline (615.213 us; speedup 1.0000x reference)
//
// R4: occupancy + epilogue-lite. R3 post-mortem: conflicts fixed (6.3e7->5e5)
// but VGPR 84->112 dropped occupancy 33->22.5% (112+64acc=176 -> 2 waves/SIMD).
// Fix: (a) drop the xor2 merge stage -> 16 slots/row (32KB union, still free),
// fewer VALU ops + fewer live temps; (b) __launch_bounds__(256,3) to force
// 3 waves/SIMD (arch VGPR ~<=104 incl. 64 AGPR acc).
#include <hip/hip_runtime.h>
#include <stdint.h>

#define N_TOK   16384
#define DIM     512
#define K_CODES 8192
#define BM      128
#define BN      128
#define BK      32
#define NT      2        // BN-tiles per block (chunk = 256 codes)
#define NCHUNK  32
#define MU      0.25f    // rerank margin; fp16 score err sigma ~0.015

typedef __attribute__((ext_vector_type(8))) _Float16 f16x8;
typedef __attribute__((ext_vector_type(4))) _Float16 f16x4;
typedef __attribute__((ext_vector_type(4))) float f32x4;
typedef __attribute__((ext_vector_type(2))) unsigned long long u64x2;

__device__ __forceinline__ unsigned int fmono(float f) {
  unsigned int b = __float_as_uint(f);
  unsigned int mask = ((int)b < 0) ? 0xFFFFFFFFu : 0x80000000u;
  return b ^ mask;
}
__device__ __forceinline__ float finv(unsigned int m) {
  return (m & 0x80000000u) ? __uint_as_float(m ^ 0x80000000u)
                           : __uint_as_float(~m);
}
__device__ __forceinline__ void async16(const void* gptr, void* lptr) {
  __builtin_amdgcn_global_load_lds(
      (const __attribute__((address_space(1))) unsigned int*)gptr,
      (__attribute__((address_space(3))) unsigned int*)lptr,
      16, 0, 0);
}
__device__ __forceinline__ unsigned long long shflx(unsigned long long v, int x) {
  const int lo = __shfl_xor((int)(unsigned int)v, x, 64);
  const int hi = __shfl_xor((int)(unsigned int)(v >> 32), x, 64);
  return ((unsigned long long)(unsigned int)hi << 32) | (unsigned int)lo;
}
__device__ __forceinline__ unsigned long long umin64(unsigned long long a,
                                                     unsigned long long b) {
  return a < b ? a : b;
}
__device__ __forceinline__ unsigned long long umax64(unsigned long long a,
                                                     unsigned long long b) {
  return a < b ? b : a;
}

// ---------------- cast X: fp32 -> fp16 ----------------
__global__ __launch_bounds__(256) void castx_kernel(
    const float* __restrict__ in, _Float16* __restrict__ out) {
  const int gid = blockIdx.x * 256 + threadIdx.x;   // one float4 each
  const float4 v = ((const float4*)in)[gid];
  f16x4 h;
  h.x = (_Float16)v.x; h.y = (_Float16)v.y;
  h.z = (_Float16)v.z; h.w = (_Float16)v.w;
  *(f16x4*)(out + (size_t)gid * 4) = h;
}

// ---------------- enorm (fp64-exact) + cast E: fp32 -> fp16 ----------------
__global__ __launch_bounds__(256) void enorm_cast_kernel(
    const float* __restrict__ ew, float* __restrict__ enorm,
    _Float16* __restrict__ E16) {
  const int lane = threadIdx.x & 63;
  const int wid  = threadIdx.x >> 6;
  const int row  = blockIdx.x * 4 + wid;
  const float4 v0 = *(const float4*)(ew + (size_t)row * DIM + lane * 8);
  const float4 v1 = *(const float4*)(ew + (size_t)row * DIM + lane * 8 + 4);
  const float f[8] = {v0.x, v0.y, v0.z, v0.w, v1.x, v1.y, v1.z, v1.w};
  f16x8 h;
  double s = 0.0;
#pragma unroll
  for (int k = 0; k < 8; ++k) {
    s = fma((double)f[k], (double)f[k], s);
    h[k] = (_Float16)f[k];
  }
  *(f16x8*)(E16 + (size_t)row * DIM + lane * 8) = h;
#pragma unroll
  for (int off = 32; off > 0; off >>= 1) s += __shfl_down(s, off, 64);
  if (lane == 0) enorm[row] = (float)s;
}

// ---------------- main: fp16 K=512 GEMM + per-chunk top-2 ----------------
// score(i,k) = ||e_k||^2 - 2*x_i.e_k  (fp16 operands, fp32 MFMA accumulate)
// Atomic-free epilogue: per-thread top-2 over j, ONE xor1 shuffle merge
// (sorted-pair merge associative over disjoint column sets), even lanes
// write their pair to one of 16 slots/row. Two waves sharing a row own
// disjoint slot halves: slot = (wid&1)*8 + (l15>>1), swizzled ^(row&7)
// (bits 0-2 only -> halves stay disjoint; bijective). Scanner merges all
// 16 physical slots per row into register-resident running top-2.
// Merge buffer (32KB) aliases As/Bs via union: written only after the
// k-loop's final barrier, scanned before next nt's staging.
__global__ __launch_bounds__(256, 3) void gemm_top2_kernel(
    const _Float16* __restrict__ X16,   // N x 512
    const _Float16* __restrict__ E16,   // K x 512
    const float* __restrict__ enorm,
    unsigned long long* __restrict__ buf1,   // [token][32] packed top-1
    unsigned long long* __restrict__ buf2) { // [token][32] packed top-2
  __shared__ __align__(16) union {
    struct { _Float16 A[BM * BK]; _Float16 B[BN * BK]; } t;  // 8KB + 8KB
    unsigned long long mg[BM][16][2];                         // 32KB merge
  } sh;

  const int tid  = threadIdx.x;
  const int lane = tid & 63;
  const int wid  = tid >> 6;
  const int quad = lane >> 4;
  const int l15  = lane & 15;

  const int row0 = blockIdx.y * BM;

  const int wm = (wid >> 1) * 64;
  const int wn = (wid & 1) * 64;

  // staging (baseline-verified): issue covers 16 rows x 64B; lane ->
  // row lane>>2, phys slot lane&3, fetched logical chunk (lane&3)^((lane>>3)&3)
  const int issue0 = wid * 2;
  const int srow   = lane >> 2;
  const int schunk = (lane & 3) ^ ((lane >> 3) & 3);

  // running top-2 across NT chunks (only meaningful for tid < BM)
  unsigned long long g1 = ~0ull, g2 = ~0ull;

  for (int nt = 0; nt < NT; ++nt) {
    const int nbase = blockIdx.x * (BN * NT) + nt * BN;

    f32x4 acc[4][4];
#pragma unroll
    for (int i = 0; i < 4; ++i)
#pragma unroll
      for (int j = 0; j < 4; ++j) acc[i][j] = (f32x4){0.f, 0.f, 0.f, 0.f};

    for (int k0 = 0; k0 < DIM; k0 += BK) {
#pragma unroll
      for (int q = 0; q < 2; ++q) {
        const int issue = issue0 + q;
        const int r = issue * 16 + srow;
        async16(X16 + (size_t)(row0 + r) * DIM + k0 + schunk * 8,
                (char*)sh.t.A + issue * 1024);
        async16(E16 + (size_t)(nbase + r) * DIM + k0 + schunk * 8,
                (char*)sh.t.B + issue * 1024);
      }
      __syncthreads();
      f16x8 a[4], b[4];
#pragma unroll
      for (int i = 0; i < 4; ++i) {
        const int ra = wm + i * 16 + l15;
        a[i] = *(const f16x8*)((const char*)sh.t.A + ra * 64 + ((quad ^ ((ra >> 1) & 3)) * 16));
        const int rb = wn + i * 16 + l15;
        b[i] = *(const f16x8*)((const char*)sh.t.B + rb * 64 + ((quad ^ ((rb >> 1) & 3)) * 16));
      }
#pragma unroll
      for (int i = 0; i < 4; ++i)
#pragma unroll
        for (int j = 0; j < 4; ++j)
          acc[i][j] = __builtin_amdgcn_mfma_f32_16x16x32_f16(a[i], b[j], acc[i][j], 0, 0, 0);
      __syncthreads();
    }

    // ---- epilogue (atomic-free, single shuffle merge) ----
    float en4[4];
#pragma unroll
    for (int j = 0; j < 4; ++j) en4[j] = enorm[nbase + wn + j * 16 + l15];

#pragma unroll
    for (int i = 0; i < 4; ++i) {
      const int mrow = wm + i * 16 + quad * 4;
#pragma unroll
      for (int r = 0; r < 4; ++r) {
        float b1 = __builtin_inff(), b2v = __builtin_inff();
        unsigned int b1i = 0u, b2i = 0u;
#pragma unroll
        for (int j = 0; j < 4; ++j) {
          const float v = fmaf(-2.f, acc[i][j][r], en4[j]);
          const unsigned int ng = (unsigned int)(nbase + wn + j * 16 + l15);
          if (v < b1) { b2v = b1; b2i = b1i; b1 = v; b1i = ng; }
          else if (v < b2v) { b2v = v; b2i = ng; }
        }
        unsigned long long p1 =
            ((unsigned long long)fmono(b1) << 32) | (unsigned long long)b1i;
        unsigned long long p2 =
            ((unsigned long long)fmono(b2v) << 32) | (unsigned long long)b2i;
        // xor1 merge (lane pairs {0,1},{2,3},... same quad -> same row,
        // disjoint column sets)
        {
          const unsigned long long q1 = shflx(p1, 1);
          const unsigned long long q2 = shflx(p2, 1);
          const unsigned long long hi = umax64(p1, q1);
          p1 = umin64(p1, q1);
          p2 = umin64(hi, umin64(p2, q2));
        }
        if (!(lane & 1)) {
          const int row = mrow + r;
          u64x2 w; w.x = p1; w.y = p2;
          // 16 writers/row across 2 waves -> 16 distinct slots (disjoint
          // halves by wid&1; ^(row&7) touches bits 0-2 only, bijective).
          *(u64x2*)&sh.mg[row][((wid & 1) * 8 + (l15 >> 1)) ^ (row & 7)][0] = w;
        }
      }
    }
    __syncthreads();

    if (tid < BM) {
#pragma unroll
      for (int s = 0; s < 16; ++s) {
        // ^(tid&7) spreads banks across rows (writer-side swizzle match);
        // enumeration order is irrelevant to the merge.
        const u64x2 v = *(const u64x2*)&sh.mg[tid][s ^ (tid & 7)][0];
        const unsigned long long v1 = v.x, v2 = v.y;
        const unsigned long long lo = umin64(v1, g1);
        const unsigned long long hi = umax64(v1, g1);
        g1 = lo;
        g2 = umin64(hi, umin64(v2, g2));
      }
    }
    __syncthreads();   // protect mg from next nt's staging into A/B
  }

  if (tid < BM) {
    buf1[(size_t)(row0 + tid) * NCHUNK + blockIdx.x] = g1;
    buf2[(size_t)(row0 + tid) * NCHUNK + blockIdx.x] = g2;
  }
}

// ---------------- fused: exact fp64 rerank + gather + loss ----------------
// One wave per token. Butterfly reductions leave results in ALL lanes, so the
// whole wave agrees on the winner and gathers/writes the output row itself.
__global__ __launch_bounds__(256) void rerank_gather_loss_kernel(
    const float* __restrict__ xs, const float* __restrict__ ew,
    const unsigned long long* __restrict__ buf1,
    const unsigned long long* __restrict__ buf2,
    float* __restrict__ out, float* __restrict__ loss_acc) {
  const int lane = threadIdx.x & 63;
  const int wv = threadIdx.x >> 6;
  const int tok = blockIdx.x * 4 + wv;
  const unsigned long long p = (lane < 32)
      ? buf1[(size_t)tok * NCHUNK + lane]
      : buf2[(size_t)tok * NCHUNK + (lane - 32)];
  const float S = finv((unsigned int)(p >> 32));
  float m = S;
#pragma unroll
  for (int off = 32; off > 0; off >>= 1) m = fminf(m, __shfl_xor(m, off, 64));
  unsigned long long mask = __ballot(S < m + MU);

  const float4 x0 = *(const float4*)(xs + (size_t)tok * DIM + lane * 8);
  const float4 x1 = *(const float4*)(xs + (size_t)tok * DIM + lane * 8 + 4);
  const double xd[8] = {x0.x, x0.y, x0.z, x0.w, x1.x, x1.y, x1.z, x1.w};

  double best = __builtin_inf();
  unsigned int besti = 0xFFFFFFFFu;
  while (mask) {
    const int src = __ffsll(mask) - 1;
    mask &= mask - 1;
    const unsigned int ci = (unsigned int)__shfl((int)(unsigned int)p, src, 64);
    const float4 e0 = *(const float4*)(ew + (size_t)ci * DIM + lane * 8);
    const float4 e1 = *(const float4*)(ew + (size_t)ci * DIM + lane * 8 + 4);
    const double ed[8] = {e0.x, e0.y, e0.z, e0.w, e1.x, e1.y, e1.z, e1.w};
    double s = 0.0;
#pragma unroll
    for (int k = 0; k < 8; ++k) {
      const double d = xd[k] - ed[k];
      s = fma(d, d, s);
    }
#pragma unroll
    for (int off = 32; off > 0; off >>= 1) s += __shfl_xor(s, off, 64);
    if (s < best || (s == best && ci < besti)) { best = s; besti = ci; }
  }

  // gather winner row + loss partial (all lanes agree on besti)
  const float4 e0 = *(const float4*)(ew + (size_t)besti * DIM + lane * 8);
  const float4 e1 = *(const float4*)(ew + (size_t)besti * DIM + lane * 8 + 4);
  *(float4*)(out + (size_t)tok * DIM + lane * 8) = e0;
  *(float4*)(out + (size_t)tok * DIM + lane * 8 + 4) = e1;
  const float ef[8] = {e0.x, e0.y, e0.z, e0.w, e1.x, e1.y, e1.z, e1.w};
  const float xf[8] = {x0.x, x0.y, x0.z, x0.w, x1.x, x1.y, x1.z, x1.w};
  float ls = 0.f;
#pragma unroll
  for (int k = 0; k < 8; ++k) {
    const float d = ef[k] - xf[k];
    ls = fmaf(d, d, ls);
  }
#pragma unroll
  for (int off = 32; off > 0; off >>= 1) ls += __shfl_xor(ls, off, 64);
  if (lane == 0) atomicAdd(loss_acc, ls);
}

__global__ void loss_finalize(const float* __restrict__ loss_acc,
                              float* __restrict__ out, int out_size) {
  if (threadIdx.x == 0 && blockIdx.x == 0)
    out[out_size - 1] = *loss_acc * 1.25f / (float)((size_t)N_TOK * DIM);
}

// ---------------- fallback: R5 exact fp64 brute (known-passing) ----------------
#define TT 16
#define CT 16
#define KH 256
#define XPAD 516
#define EPAD 260
__global__ __launch_bounds__(256) void brute_argmin_kernel(
    const float* __restrict__ xs, const float* __restrict__ ew,
    unsigned int* __restrict__ g_idx) {
  __shared__ __align__(16) float Xs[TT * XPAD];
  __shared__ __align__(16) float Es[CT * EPAD];
  __shared__ double cand_v[256];
  __shared__ unsigned int cand_i[256];
  const int t = threadIdx.x;
  const int tok0 = blockIdx.x * TT;
#pragma unroll
  for (int i = 0; i < 32; ++i) {
    const int idx = i * 256 + t;
    const int row = idx >> 9, col = idx & 511;
    Xs[row * XPAD + col] = xs[(size_t)(tok0 + row) * DIM + col];
  }
  const int tt = t >> 4;
  const int cl = t & 15;
  double bv = __builtin_inf();
  unsigned int bi = 0u;
  for (int c0 = 0; c0 < K_CODES; c0 += CT) {
    double s0 = 0.0, s1 = 0.0, s2 = 0.0, s3 = 0.0;
#pragma unroll
    for (int h = 0; h < 2; ++h) {
      __syncthreads();
#pragma unroll
      for (int i = 0; i < 16; ++i) {
        const int idx = i * 256 + t;
        const int row = idx >> 8, col = idx & 255;
        Es[row * EPAD + col] = ew[(size_t)(c0 + row) * DIM + h * KH + col];
      }
      __syncthreads();
      const float* __restrict__ xr = &Xs[tt * XPAD + h * KH];
      const float* __restrict__ er = &Es[cl * EPAD];
#pragma unroll 8
      for (int d = 0; d < KH; d += 4) {
        const float4 xf = *(const float4*)(xr + d);
        const float4 ef = *(const float4*)(er + d);
        const double a0 = (double)xf.x - (double)ef.x;
        const double a1 = (double)xf.y - (double)ef.y;
        const double a2 = (double)xf.z - (double)ef.z;
        const double a3 = (double)xf.w - (double)ef.w;
        s0 = fma(a0, a0, s0); s1 = fma(a1, a1, s1);
        s2 = fma(a2, a2, s2); s3 = fma(a3, a3, s3);
      }
    }
    const double s = (s0 + s1) + (s2 + s3);
    if (s < bv) { bv = s; bi = (unsigned int)(c0 + cl); }
  }
  cand_v[t] = bv; cand_i[t] = bi;
  __syncthreads();
  if (t < TT) {
    double mv = __builtin_inf();
    unsigned int mi = 0xFFFFFFFFu;
#pragma unroll
    for (int j = 0; j < 16; ++j) {
      const double v = cand_v[t * 16 + j];
      const unsigned int i = cand_i[t * 16 + j];
      if (v < mv || (v == mv && i < mi)) { mv = v; mi = i; }
    }
    g_idx[tok0 + t] = mi;
  }
}

__global__ __launch_bounds__(256) void gather_loss_kernel(
    const float* __restrict__ xs, const float* __restrict__ ew,
    const unsigned int* __restrict__ g_idx,
    float* __restrict__ out, float* __restrict__ loss_acc) {
  const int row = blockIdx.x;
  const int t = threadIdx.x;
  const unsigned int idx = g_idx[row];
  const float2 ev = ((const float2*)(ew + (size_t)idx * DIM))[t];
  const float2 xv = ((const float2*)(xs + (size_t)row * DIM))[t];
  ((float2*)(out + (size_t)row * DIM))[t] = ev;
  const float d0 = ev.x - xv.x;
  const float d1 = ev.y - xv.y;
  float s = fmaf(d0, d0, d1 * d1);
#pragma unroll
  for (int off = 32; off > 0; off >>= 1) s += __shfl_down(s, off, 64);
  __shared__ float wsum[4];
  if ((t & 63) == 0) wsum[t >> 6] = s;
  __syncthreads();
  if (t == 0) atomicAdd(loss_acc, wsum[0] + wsum[1] + wsum[2] + wsum[3]);
}

// ---------------- launch ----------------
extern "C" void kernel_launch(void* const* d_in, const int* in_sizes, int n_in,
                              void* d_out, int out_size, void* d_ws, size_t ws_size,
                              hipStream_t stream) {
  const float* xs = (const float*)d_in[0];
  const float* ew = (const float*)d_in[1];
  if (n_in >= 2 && in_sizes[0] == K_CODES * DIM && in_sizes[1] == N_TOK * DIM) {
    const float* tmp = xs; xs = ew; ew = tmp;
  }
  float* out = (float*)d_out;

  char* w = (char*)d_ws;
  _Float16* X16 = (_Float16*)(w);                                   // 16 MB
  _Float16* E16 = (_Float16*)(w + 16777216);                        // 8 MB
  float* enorm = (float*)(w + 25165824);                            // 32 KB
  unsigned long long* buf1 = (unsigned long long*)(w + 25198592);   // 4 MB
  unsigned long long* buf2 = (unsigned long long*)(w + 29392896);   // 4 MB
  float* loss_acc = (float*)(w + 33587200);
  const size_t NEED = 33587264;

  if (ws_size < NEED) {   // fallback: proven R5 exact path
    unsigned int* fg_idx = (unsigned int*)d_ws;
    float* floss = (float*)((char*)d_ws + (size_t)N_TOK * 4);
    hipMemsetAsync(floss, 0, 4, stream);
    brute_argmin_kernel<<<N_TOK / TT, 256, 0, stream>>>(xs, ew, fg_idx);
    gather_loss_kernel<<<N_TOK, 256, 0, stream>>>(xs, ew, fg_idx, out, floss);
    loss_finalize<<<1, 64, 0, stream>>>(floss, out, out_size);
    return;
  }

  hipMemsetAsync(loss_acc, 0, 4, stream);

  castx_kernel<<<N_TOK * DIM / 4 / 256, 256, 0, stream>>>(xs, X16);
  enorm_cast_kernel<<<K_CODES / 4, 256, 0, stream>>>(ew, enorm, E16);

  dim3 g2(K_CODES / (BN * NT), N_TOK / BM);   // 32 x 128
  gemm_top2_kernel<<<g2, 256, 0, stream>>>(X16, E16, enorm, buf1, buf2);

  rerank_gather_loss_kernel<<<N_TOK / 4, 256, 0, stream>>>(xs, ew, buf1, buf2,
                                                           out, loss_acc);
  loss_finalize<<<1, 64, 0, stream>>>(loss_acc, out, out_size);
}

// Round 5
// 570.819 us; speedup vs baseline: 1.0778x; 1.0778x over previous
//
// R5: revert R4's forced launch_bounds (spill signature confirmed: +450MB/dispatch
// scratch traffic, dur 316->331). Keep R4's light 1-stage epilogue. New: split
// MFMA block into two j-halves to halve b-frag liveness (-8 VGPR peak), hoist
// code-index base. Goal: natural VGPR <= ~106 (+64 AGPR -> 3 waves/SIMD).
#include <hip/hip_runtime.h>
#include <stdint.h>

#define N_TOK   16384
#define DIM     512
#define K_CODES 8192
#define BM      128
#define BN      128
#define BK      32
#define NT      2        // BN-tiles per block (chunk = 256 codes)
#define NCHUNK  32
#define MU      0.25f    // rerank margin; fp16 score err sigma ~0.015

typedef __attribute__((ext_vector_type(8))) _Float16 f16x8;
typedef __attribute__((ext_vector_type(4))) _Float16 f16x4;
typedef __attribute__((ext_vector_type(4))) float f32x4;
typedef __attribute__((ext_vector_type(2))) unsigned long long u64x2;

__device__ __forceinline__ unsigned int fmono(float f) {
  unsigned int b = __float_as_uint(f);
  unsigned int mask = ((int)b < 0) ? 0xFFFFFFFFu : 0x80000000u;
  return b ^ mask;
}
__device__ __forceinline__ float finv(unsigned int m) {
  return (m & 0x80000000u) ? __uint_as_float(m ^ 0x80000000u)
                           : __uint_as_float(~m);
}
__device__ __forceinline__ void async16(const void* gptr, void* lptr) {
  __builtin_amdgcn_global_load_lds(
      (const __attribute__((address_space(1))) unsigned int*)gptr,
      (__attribute__((address_space(3))) unsigned int*)lptr,
      16, 0, 0);
}
__device__ __forceinline__ unsigned long long shflx(unsigned long long v, int x) {
  const int lo = __shfl_xor((int)(unsigned int)v, x, 64);
  const int hi = __shfl_xor((int)(unsigned int)(v >> 32), x, 64);
  return ((unsigned long long)(unsigned int)hi << 32) | (unsigned int)lo;
}
__device__ __forceinline__ unsigned long long umin64(unsigned long long a,
                                                     unsigned long long b) {
  return a < b ? a : b;
}
__device__ __forceinline__ unsigned long long umax64(unsigned long long a,
                                                     unsigned long long b) {
  return a < b ? b : a;
}

// ---------------- cast X: fp32 -> fp16 ----------------
__global__ __launch_bounds__(256) void castx_kernel(
    const float* __restrict__ in, _Float16* __restrict__ out) {
  const int gid = blockIdx.x * 256 + threadIdx.x;   // one float4 each
  const float4 v = ((const float4*)in)[gid];
  f16x4 h;
  h.x = (_Float16)v.x; h.y = (_Float16)v.y;
  h.z = (_Float16)v.z; h.w = (_Float16)v.w;
  *(f16x4*)(out + (size_t)gid * 4) = h;
}

// ---------------- enorm (fp64-exact) + cast E: fp32 -> fp16 ----------------
__global__ __launch_bounds__(256) void enorm_cast_kernel(
    const float* __restrict__ ew, float* __restrict__ enorm,
    _Float16* __restrict__ E16) {
  const int lane = threadIdx.x & 63;
  const int wid  = threadIdx.x >> 6;
  const int row  = blockIdx.x * 4 + wid;
  const float4 v0 = *(const float4*)(ew + (size_t)row * DIM + lane * 8);
  const float4 v1 = *(const float4*)(ew + (size_t)row * DIM + lane * 8 + 4);
  const float f[8] = {v0.x, v0.y, v0.z, v0.w, v1.x, v1.y, v1.z, v1.w};
  f16x8 h;
  double s = 0.0;
#pragma unroll
  for (int k = 0; k < 8; ++k) {
    s = fma((double)f[k], (double)f[k], s);
    h[k] = (_Float16)f[k];
  }
  *(f16x8*)(E16 + (size_t)row * DIM + lane * 8) = h;
#pragma unroll
  for (int off = 32; off > 0; off >>= 1) s += __shfl_down(s, off, 64);
  if (lane == 0) enorm[row] = (float)s;
}

// ---------------- main: fp16 K=512 GEMM + per-chunk top-2 ----------------
// score(i,k) = ||e_k||^2 - 2*x_i.e_k  (fp16 operands, fp32 MFMA accumulate)
// Atomic-free epilogue: per-thread top-2 over j, ONE xor1 shuffle merge
// (sorted-pair merge associative over disjoint column sets), even lanes
// write their pair to one of 16 slots/row. Two waves sharing a row own
// disjoint slot halves: slot = (wid&1)*8 + (l15>>1), swizzled ^(row&7)
// (bits 0-2 only -> halves stay disjoint; bijective). Scanner merges all
// 16 physical slots per row into register-resident running top-2.
// Merge buffer (32KB) aliases As/Bs via union: written only after the
// k-loop's final barrier, scanned before next nt's staging.
__global__ __launch_bounds__(256) void gemm_top2_kernel(
    const _Float16* __restrict__ X16,   // N x 512
    const _Float16* __restrict__ E16,   // K x 512
    const float* __restrict__ enorm,
    unsigned long long* __restrict__ buf1,   // [token][32] packed top-1
    unsigned long long* __restrict__ buf2) { // [token][32] packed top-2
  __shared__ __align__(16) union {
    struct { _Float16 A[BM * BK]; _Float16 B[BN * BK]; } t;  // 8KB + 8KB
    unsigned long long mg[BM][16][2];                         // 32KB merge
  } sh;

  const int tid  = threadIdx.x;
  const int lane = tid & 63;
  const int wid  = tid >> 6;
  const int quad = lane >> 4;
  const int l15  = lane & 15;

  const int row0 = blockIdx.y * BM;

  const int wm = (wid >> 1) * 64;
  const int wn = (wid & 1) * 64;

  // staging (baseline-verified): issue covers 16 rows x 64B; lane ->
  // row lane>>2, phys slot lane&3, fetched logical chunk (lane&3)^((lane>>3)&3)
  const int issue0 = wid * 2;
  const int srow   = lane >> 2;
  const int schunk = (lane & 3) ^ ((lane >> 3) & 3);

  // running top-2 across NT chunks (only meaningful for tid < BM)
  unsigned long long g1 = ~0ull, g2 = ~0ull;

  for (int nt = 0; nt < NT; ++nt) {
    const int nbase = blockIdx.x * (BN * NT) + nt * BN;

    f32x4 acc[4][4];
#pragma unroll
    for (int i = 0; i < 4; ++i)
#pragma unroll
      for (int j = 0; j < 4; ++j) acc[i][j] = (f32x4){0.f, 0.f, 0.f, 0.f};

    for (int k0 = 0; k0 < DIM; k0 += BK) {
#pragma unroll
      for (int q = 0; q < 2; ++q) {
        const int issue = issue0 + q;
        const int r = issue * 16 + srow;
        async16(X16 + (size_t)(row0 + r) * DIM + k0 + schunk * 8,
                (char*)sh.t.A + issue * 1024);
        async16(E16 + (size_t)(nbase + r) * DIM + k0 + schunk * 8,
                (char*)sh.t.B + issue * 1024);
      }
      __syncthreads();
      f16x8 a[4];
#pragma unroll
      for (int i = 0; i < 4; ++i) {
        const int ra = wm + i * 16 + l15;
        a[i] = *(const f16x8*)((const char*)sh.t.A + ra * 64 + ((quad ^ ((ra >> 1) & 3)) * 16));
      }
      // two j-halves: halves concurrent b-frag liveness (8 VGPR peak saved);
      // ds_read latency of each half hides under the 8 MFMAs of the half.
#pragma unroll
      for (int jh = 0; jh < 2; ++jh) {
        const int rb0 = wn + (jh * 2 + 0) * 16 + l15;
        const int rb1 = wn + (jh * 2 + 1) * 16 + l15;
        const f16x8 b0 = *(const f16x8*)((const char*)sh.t.B + rb0 * 64 + ((quad ^ ((rb0 >> 1) & 3)) * 16));
        const f16x8 b1 = *(const f16x8*)((const char*)sh.t.B + rb1 * 64 + ((quad ^ ((rb1 >> 1) & 3)) * 16));
#pragma unroll
        for (int i = 0; i < 4; ++i) {
          acc[i][jh * 2 + 0] = __builtin_amdgcn_mfma_f32_16x16x32_f16(a[i], b0, acc[i][jh * 2 + 0], 0, 0, 0);
          acc[i][jh * 2 + 1] = __builtin_amdgcn_mfma_f32_16x16x32_f16(a[i], b1, acc[i][jh * 2 + 1], 0, 0, 0);
        }
      }
      __syncthreads();
    }

    // ---- epilogue (atomic-free, single shuffle merge) ----
    float en4[4];
#pragma unroll
    for (int j = 0; j < 4; ++j) en4[j] = enorm[nbase + wn + j * 16 + l15];
    const unsigned int ngb = (unsigned int)(nbase + wn + l15);

#pragma unroll
    for (int i = 0; i < 4; ++i) {
      const int mrow = wm + i * 16 + quad * 4;
#pragma unroll
      for (int r = 0; r < 4; ++r) {
        float b1 = __builtin_inff(), b2v = __builtin_inff();
        unsigned int b1i = 0u, b2i = 0u;
#pragma unroll
        for (int j = 0; j < 4; ++j) {
          const float v = fmaf(-2.f, acc[i][j][r], en4[j]);
          const unsigned int ng = ngb + j * 16;
          if (v < b1) { b2v = b1; b2i = b1i; b1 = v; b1i = ng; }
          else if (v < b2v) { b2v = v; b2i = ng; }
        }
        unsigned long long p1 =
            ((unsigned long long)fmono(b1) << 32) | (unsigned long long)b1i;
        unsigned long long p2 =
            ((unsigned long long)fmono(b2v) << 32) | (unsigned long long)b2i;
        // xor1 merge (lane pairs {0,1},{2,3},... same quad -> same row,
        // disjoint column sets)
        {
          const unsigned long long q1 = shflx(p1, 1);
          const unsigned long long q2 = shflx(p2, 1);
          const unsigned long long hi = umax64(p1, q1);
          p1 = umin64(p1, q1);
          p2 = umin64(hi, umin64(p2, q2));
        }
        if (!(lane & 1)) {
          const int row = mrow + r;
          u64x2 w; w.x = p1; w.y = p2;
          // 16 writers/row across 2 waves -> 16 distinct slots (disjoint
          // halves by wid&1; ^(row&7) touches bits 0-2 only, bijective).
          *(u64x2*)&sh.mg[row][((wid & 1) * 8 + (l15 >> 1)) ^ (row & 7)][0] = w;
        }
      }
    }
    __syncthreads();

    if (tid < BM) {
#pragma unroll
      for (int s = 0; s < 16; ++s) {
        // ^(tid&7) spreads banks across rows (writer-side swizzle match);
        // enumeration order is irrelevant to the merge.
        const u64x2 v = *(const u64x2*)&sh.mg[tid][s ^ (tid & 7)][0];
        const unsigned long long v1 = v.x, v2 = v.y;
        const unsigned long long lo = umin64(v1, g1);
        const unsigned long long hi = umax64(v1, g1);
        g1 = lo;
        g2 = umin64(hi, umin64(v2, g2));
      }
    }
    __syncthreads();   // protect mg from next nt's staging into A/B
  }

  if (tid < BM) {
    buf1[(size_t)(row0 + tid) * NCHUNK + blockIdx.x] = g1;
    buf2[(size_t)(row0 + tid) * NCHUNK + blockIdx.x] = g2;
  }
}

// ---------------- fused: exact fp64 rerank + gather + loss ----------------
// One wave per token. Butterfly reductions leave results in ALL lanes, so the
// whole wave agrees on the winner and gathers/writes the output row itself.
__global__ __launch_bounds__(256) void rerank_gather_loss_kernel(
    const float* __restrict__ xs, const float* __restrict__ ew,
    const unsigned long long* __restrict__ buf1,
    const unsigned long long* __restrict__ buf2,
    float* __restrict__ out, float* __restrict__ loss_acc) {
  const int lane = threadIdx.x & 63;
  const int wv = threadIdx.x >> 6;
  const int tok = blockIdx.x * 4 + wv;
  const unsigned long long p = (lane < 32)
      ? buf1[(size_t)tok * NCHUNK + lane]
      : buf2[(size_t)tok * NCHUNK + (lane - 32)];
  const float S = finv((unsigned int)(p >> 32));
  float m = S;
#pragma unroll
  for (int off = 32; off > 0; off >>= 1) m = fminf(m, __shfl_xor(m, off, 64));
  unsigned long long mask = __ballot(S < m + MU);

  const float4 x0 = *(const float4*)(xs + (size_t)tok * DIM + lane * 8);
  const float4 x1 = *(const float4*)(xs + (size_t)tok * DIM + lane * 8 + 4);
  const double xd[8] = {x0.x, x0.y, x0.z, x0.w, x1.x, x1.y, x1.z, x1.w};

  double best = __builtin_inf();
  unsigned int besti = 0xFFFFFFFFu;
  while (mask) {
    const int src = __ffsll(mask) - 1;
    mask &= mask - 1;
    const unsigned int ci = (unsigned int)__shfl((int)(unsigned int)p, src, 64);
    const float4 e0 = *(const float4*)(ew + (size_t)ci * DIM + lane * 8);
    const float4 e1 = *(const float4*)(ew + (size_t)ci * DIM + lane * 8 + 4);
    const double ed[8] = {e0.x, e0.y, e0.z, e0.w, e1.x, e1.y, e1.z, e1.w};
    double s = 0.0;
#pragma unroll
    for (int k = 0; k < 8; ++k) {
      const double d = xd[k] - ed[k];
      s = fma(d, d, s);
    }
#pragma unroll
    for (int off = 32; off > 0; off >>= 1) s += __shfl_xor(s, off, 64);
    if (s < best || (s == best && ci < besti)) { best = s; besti = ci; }
  }

  // gather winner row + loss partial (all lanes agree on besti)
  const float4 e0 = *(const float4*)(ew + (size_t)besti * DIM + lane * 8);
  const float4 e1 = *(const float4*)(ew + (size_t)besti * DIM + lane * 8 + 4);
  *(float4*)(out + (size_t)tok * DIM + lane * 8) = e0;
  *(float4*)(out + (size_t)tok * DIM + lane * 8 + 4) = e1;
  const float ef[8] = {e0.x, e0.y, e0.z, e0.w, e1.x, e1.y, e1.z, e1.w};
  const float xf[8] = {x0.x, x0.y, x0.z, x0.w, x1.x, x1.y, x1.z, x1.w};
  float ls = 0.f;
#pragma unroll
  for (int k = 0; k < 8; ++k) {
    const float d = ef[k] - xf[k];
    ls = fmaf(d, d, ls);
  }
#pragma unroll
  for (int off = 32; off > 0; off >>= 1) ls += __shfl_xor(ls, off, 64);
  if (lane == 0) atomicAdd(loss_acc, ls);
}

__global__ void loss_finalize(const float* __restrict__ loss_acc,
                              float* __restrict__ out, int out_size) {
  if (threadIdx.x == 0 && blockIdx.x == 0)
    out[out_size - 1] = *loss_acc * 1.25f / (float)((size_t)N_TOK * DIM);
}

// ---------------- fallback: R5 exact fp64 brute (known-passing) ----------------
#define TT 16
#define CT 16
#define KH 256
#define XPAD 516
#define EPAD 260
__global__ __launch_bounds__(256) void brute_argmin_kernel(
    const float* __restrict__ xs, const float* __restrict__ ew,
    unsigned int* __restrict__ g_idx) {
  __shared__ __align__(16) float Xs[TT * XPAD];
  __shared__ __align__(16) float Es[CT * EPAD];
  __shared__ double cand_v[256];
  __shared__ unsigned int cand_i[256];
  const int t = threadIdx.x;
  const int tok0 = blockIdx.x * TT;
#pragma unroll
  for (int i = 0; i < 32; ++i) {
    const int idx = i * 256 + t;
    const int row = idx >> 9, col = idx & 511;
    Xs[row * XPAD + col] = xs[(size_t)(tok0 + row) * DIM + col];
  }
  const int tt = t >> 4;
  const int cl = t & 15;
  double bv = __builtin_inf();
  unsigned int bi = 0u;
  for (int c0 = 0; c0 < K_CODES; c0 += CT) {
    double s0 = 0.0, s1 = 0.0, s2 = 0.0, s3 = 0.0;
#pragma unroll
    for (int h = 0; h < 2; ++h) {
      __syncthreads();
#pragma unroll
      for (int i = 0; i < 16; ++i) {
        const int idx = i * 256 + t;
        const int row = idx >> 8, col = idx & 255;
        Es[row * EPAD + col] = ew[(size_t)(c0 + row) * DIM + h * KH + col];
      }
      __syncthreads();
      const float* __restrict__ xr = &Xs[tt * XPAD + h * KH];
      const float* __restrict__ er = &Es[cl * EPAD];
#pragma unroll 8
      for (int d = 0; d < KH; d += 4) {
        const float4 xf = *(const float4*)(xr + d);
        const float4 ef = *(const float4*)(er + d);
        const double a0 = (double)xf.x - (double)ef.x;
        const double a1 = (double)xf.y - (double)ef.y;
        const double a2 = (double)xf.z - (double)ef.z;
        const double a3 = (double)xf.w - (double)ef.w;
        s0 = fma(a0, a0, s0); s1 = fma(a1, a1, s1);
        s2 = fma(a2, a2, s2); s3 = fma(a3, a3, s3);
      }
    }
    const double s = (s0 + s1) + (s2 + s3);
    if (s < bv) { bv = s; bi = (unsigned int)(c0 + cl); }
  }
  cand_v[t] = bv; cand_i[t] = bi;
  __syncthreads();
  if (t < TT) {
    double mv = __builtin_inf();
    unsigned int mi = 0xFFFFFFFFu;
#pragma unroll
    for (int j = 0; j < 16; ++j) {
      const double v = cand_v[t * 16 + j];
      const unsigned int i = cand_i[t * 16 + j];
      if (v < mv || (v == mv && i < mi)) { mv = v; mi = i; }
    }
    g_idx[tok0 + t] = mi;
  }
}

__global__ __launch_bounds__(256) void gather_loss_kernel(
    const float* __restrict__ xs, const float* __restrict__ ew,
    const unsigned int* __restrict__ g_idx,
    float* __restrict__ out, float* __restrict__ loss_acc) {
  const int row = blockIdx.x;
  const int t = threadIdx.x;
  const unsigned int idx = g_idx[row];
  const float2 ev = ((const float2*)(ew + (size_t)idx * DIM))[t];
  const float2 xv = ((const float2*)(xs + (size_t)row * DIM))[t];
  ((float2*)(out + (size_t)row * DIM))[t] = ev;
  const float d0 = ev.x - xv.x;
  const float d1 = ev.y - xv.y;
  float s = fmaf(d0, d0, d1 * d1);
#pragma unroll
  for (int off = 32; off > 0; off >>= 1) s += __shfl_down(s, off, 64);
  __shared__ float wsum[4];
  if ((t & 63) == 0) wsum[t >> 6] = s;
  __syncthreads();
  if (t == 0) atomicAdd(loss_acc, wsum[0] + wsum[1] + wsum[2] + wsum[3]);
}

// ---------------- launch ----------------
extern "C" void kernel_launch(void* const* d_in, const int* in_sizes, int n_in,
                              void* d_out, int out_size, void* d_ws, size_t ws_size,
                              hipStream_t stream) {
  const float* xs = (const float*)d_in[0];
  const float* ew = (const float*)d_in[1];
  if (n_in >= 2 && in_sizes[0] == K_CODES * DIM && in_sizes[1] == N_TOK * DIM) {
    const float* tmp = xs; xs = ew; ew = tmp;
  }
  float* out = (float*)d_out;

  char* w = (char*)d_ws;
  _Float16* X16 = (_Float16*)(w);                                   // 16 MB
  _Float16* E16 = (_Float16*)(w + 16777216);                        // 8 MB
  float* enorm = (float*)(w + 25165824);                            // 32 KB
  unsigned long long* buf1 = (unsigned long long*)(w + 25198592);   // 4 MB
  unsigned long long* buf2 = (unsigned long long*)(w + 29392896);   // 4 MB
  float* loss_acc = (float*)(w + 33587200);
  const size_t NEED = 33587264;

  if (ws_size < NEED) {   // fallback: proven R5 exact path
    unsigned int* fg_idx = (unsigned int*)d_ws;
    float* floss = (float*)((char*)d_ws + (size_t)N_TOK * 4);
    hipMemsetAsync(floss, 0, 4, stream);
    brute_argmin_kernel<<<N_TOK / TT, 256, 0, stream>>>(xs, ew, fg_idx);
    gather_loss_kernel<<<N_TOK, 256, 0, stream>>>(xs, ew, fg_idx, out, floss);
    loss_finalize<<<1, 64, 0, stream>>>(floss, out, out_size);
    return;
  }

  hipMemsetAsync(loss_acc, 0, 4, stream);

  castx_kernel<<<N_TOK * DIM / 4 / 256, 256, 0, stream>>>(xs, X16);
  enorm_cast_kernel<<<K_CODES / 4, 256, 0, stream>>>(ew, enorm, E16);

  dim3 g2(K_CODES / (BN * NT), N_TOK / BM);   // 32 x 128
  gemm_top2_kernel<<<g2, 256, 0, stream>>>(X16, E16, enorm, buf1, buf2);

  rerank_gather_loss_kernel<<<N_TOK / 4, 256, 0, stream>>>(xs, ew, buf1, buf2,
                                                           out, loss_acc);
  loss_finalize<<<1, 64, 0, stream>>>(loss_acc, out, out_size);
}

// Round 6
// 339.485 us; speedup vs baseline: 1.8122x; 1.6814x over previous
//
// R6: two independent fixes, separately readable in counters.
// (1) rerank: kill 16384 same-address atomicAdds (theory: the constant ~281us
//     non-gemm gap across R0/R3/R5) -> per-token partial into dead X16 region
//     + 1-block tree reduce. Zero extra workspace.
// (2) gemm: 1-phase -> 2-phase LDS double-buffer (T3-min recipe): STAGE(next)
//     overlaps compute(cur); ONE barrier per k-step (was 2). dbuf = 32KB =
//     merge-union size, occupancy unchanged.
#include <hip/hip_runtime.h>
#include <stdint.h>

#define N_TOK   16384
#define DIM     512
#define K_CODES 8192
#define BM      128
#define BN      128
#define BK      32
#define NT      2        // BN-tiles per block (chunk = 256 codes)
#define NCHUNK  32
#define MU      0.25f    // rerank margin; fp16 score err sigma ~0.015

typedef __attribute__((ext_vector_type(8))) _Float16 f16x8;
typedef __attribute__((ext_vector_type(4))) _Float16 f16x4;
typedef __attribute__((ext_vector_type(4))) float f32x4;
typedef __attribute__((ext_vector_type(2))) unsigned long long u64x2;

__device__ __forceinline__ unsigned int fmono(float f) {
  unsigned int b = __float_as_uint(f);
  unsigned int mask = ((int)b < 0) ? 0xFFFFFFFFu : 0x80000000u;
  return b ^ mask;
}
__device__ __forceinline__ float finv(unsigned int m) {
  return (m & 0x80000000u) ? __uint_as_float(m ^ 0x80000000u)
                           : __uint_as_float(~m);
}
__device__ __forceinline__ void async16(const void* gptr, void* lptr) {
  __builtin_amdgcn_global_load_lds(
      (const __attribute__((address_space(1))) unsigned int*)gptr,
      (__attribute__((address_space(3))) unsigned int*)lptr,
      16, 0, 0);
}
__device__ __forceinline__ unsigned long long shflx(unsigned long long v, int x) {
  const int lo = __shfl_xor((int)(unsigned int)v, x, 64);
  const int hi = __shfl_xor((int)(unsigned int)(v >> 32), x, 64);
  return ((unsigned long long)(unsigned int)hi << 32) | (unsigned int)lo;
}
__device__ __forceinline__ unsigned long long umin64(unsigned long long a,
                                                     unsigned long long b) {
  return a < b ? a : b;
}
__device__ __forceinline__ unsigned long long umax64(unsigned long long a,
                                                     unsigned long long b) {
  return a < b ? b : a;
}

// ---------------- cast X: fp32 -> fp16 ----------------
__global__ __launch_bounds__(256) void castx_kernel(
    const float* __restrict__ in, _Float16* __restrict__ out) {
  const int gid = blockIdx.x * 256 + threadIdx.x;   // one float4 each
  const float4 v = ((const float4*)in)[gid];
  f16x4 h;
  h.x = (_Float16)v.x; h.y = (_Float16)v.y;
  h.z = (_Float16)v.z; h.w = (_Float16)v.w;
  *(f16x4*)(out + (size_t)gid * 4) = h;
}

// ---------------- enorm (fp64-exact) + cast E: fp32 -> fp16 ----------------
__global__ __launch_bounds__(256) void enorm_cast_kernel(
    const float* __restrict__ ew, float* __restrict__ enorm,
    _Float16* __restrict__ E16) {
  const int lane = threadIdx.x & 63;
  const int wid  = threadIdx.x >> 6;
  const int row  = blockIdx.x * 4 + wid;
  const float4 v0 = *(const float4*)(ew + (size_t)row * DIM + lane * 8);
  const float4 v1 = *(const float4*)(ew + (size_t)row * DIM + lane * 8 + 4);
  const float f[8] = {v0.x, v0.y, v0.z, v0.w, v1.x, v1.y, v1.z, v1.w};
  f16x8 h;
  double s = 0.0;
#pragma unroll
  for (int k = 0; k < 8; ++k) {
    s = fma((double)f[k], (double)f[k], s);
    h[k] = (_Float16)f[k];
  }
  *(f16x8*)(E16 + (size_t)row * DIM + lane * 8) = h;
#pragma unroll
  for (int off = 32; off > 0; off >>= 1) s += __shfl_down(s, off, 64);
  if (lane == 0) enorm[row] = (float)s;
}

// ---------------- main: fp16 K=512 GEMM + per-chunk top-2 ----------------
// score(i,k) = ||e_k||^2 - 2*x_i.e_k  (fp16 operands, fp32 MFMA accumulate)
// K-loop: 2-phase LDS double-buffer. Per k-step: STAGE(buf[p^1], k+1) issued
// first (hides under compute), ds_read+MFMA on buf[p], one __syncthreads()
// (drains vmcnt+lgkmcnt; next iter's writes to buf[p] are post-barrier).
// Epilogue atomic-free: per-thread top-2 over j, ONE xor1 shuffle merge,
// even lanes write pairs to 16 slots/row (disjoint wave halves, ^(row&7)
// swizzle); scanner merges all 16 slots into register-resident running top-2.
// Merge buffer (32KB) aliases the two LDS buffers via union: written only
// after the k-loop's final barrier, scanned before next nt's staging.
__global__ __launch_bounds__(256) void gemm_top2_kernel(
    const _Float16* __restrict__ X16,   // N x 512
    const _Float16* __restrict__ E16,   // K x 512
    const float* __restrict__ enorm,
    unsigned long long* __restrict__ buf1,   // [token][32] packed top-1
    unsigned long long* __restrict__ buf2) { // [token][32] packed top-2
  __shared__ __align__(16) union {
    _Float16 buf[2][8192];            // per phase: A = bytes 0..8K, B = 8..16K
    unsigned long long mg[BM][16][2]; // 32KB merge
  } sh;

  const int tid  = threadIdx.x;
  const int lane = tid & 63;
  const int wid  = tid >> 6;
  const int quad = lane >> 4;
  const int l15  = lane & 15;

  const int row0 = blockIdx.y * BM;

  const int wm = (wid >> 1) * 64;
  const int wn = (wid & 1) * 64;

  // staging (baseline-verified): issue covers 16 rows x 64B; lane ->
  // row lane>>2, phys slot lane&3, fetched logical chunk (lane&3)^((lane>>3)&3)
  const int issue0 = wid * 2;
  const int srow   = lane >> 2;
  const int schunk = (lane & 3) ^ ((lane >> 3) & 3);

  // running top-2 across NT chunks (only meaningful for tid < BM)
  unsigned long long g1 = ~0ull, g2 = ~0ull;

  for (int nt = 0; nt < NT; ++nt) {
    const int nbase = blockIdx.x * (BN * NT) + nt * BN;

    auto STAGE = [&](int p, int k0) {
      char* base = (char*)(&sh.buf[p][0]);
#pragma unroll
      for (int q = 0; q < 2; ++q) {
        const int issue = issue0 + q;
        const int r = issue * 16 + srow;
        async16(X16 + (size_t)(row0 + r) * DIM + k0 + schunk * 8,
                base + issue * 1024);
        async16(E16 + (size_t)(nbase + r) * DIM + k0 + schunk * 8,
                base + 8192 + issue * 1024);
      }
    };

    f32x4 acc[4][4];
#pragma unroll
    for (int i = 0; i < 4; ++i)
#pragma unroll
      for (int j = 0; j < 4; ++j) acc[i][j] = (f32x4){0.f, 0.f, 0.f, 0.f};

    STAGE(0, 0);
    __syncthreads();

    for (int ks = 0; ks < DIM / BK; ++ks) {
      const int p = ks & 1;
      if (ks < DIM / BK - 1) STAGE(p ^ 1, (ks + 1) * BK);

      const char* baseA = (const char*)(&sh.buf[p][0]);
      const char* baseB = baseA + 8192;
      f16x8 a[4];
#pragma unroll
      for (int i = 0; i < 4; ++i) {
        const int ra = wm + i * 16 + l15;
        a[i] = *(const f16x8*)(baseA + ra * 64 + ((quad ^ ((ra >> 1) & 3)) * 16));
      }
      // two j-halves: halves concurrent b-frag liveness; ds_read latency of
      // each half hides under the 8 MFMAs of the half.
#pragma unroll
      for (int jh = 0; jh < 2; ++jh) {
        const int rb0 = wn + (jh * 2 + 0) * 16 + l15;
        const int rb1 = wn + (jh * 2 + 1) * 16 + l15;
        const f16x8 b0 = *(const f16x8*)(baseB + rb0 * 64 + ((quad ^ ((rb0 >> 1) & 3)) * 16));
        const f16x8 b1 = *(const f16x8*)(baseB + rb1 * 64 + ((quad ^ ((rb1 >> 1) & 3)) * 16));
#pragma unroll
        for (int i = 0; i < 4; ++i) {
          acc[i][jh * 2 + 0] = __builtin_amdgcn_mfma_f32_16x16x32_f16(a[i], b0, acc[i][jh * 2 + 0], 0, 0, 0);
          acc[i][jh * 2 + 1] = __builtin_amdgcn_mfma_f32_16x16x32_f16(a[i], b1, acc[i][jh * 2 + 1], 0, 0, 0);
        }
      }
      __syncthreads();   // drains this iter's STAGE (vmcnt) + all ds_reads
    }

    // ---- epilogue (atomic-free, single shuffle merge) ----
    float en4[4];
#pragma unroll
    for (int j = 0; j < 4; ++j) en4[j] = enorm[nbase + wn + j * 16 + l15];
    const unsigned int ngb = (unsigned int)(nbase + wn + l15);

#pragma unroll
    for (int i = 0; i < 4; ++i) {
      const int mrow = wm + i * 16 + quad * 4;
#pragma unroll
      for (int r = 0; r < 4; ++r) {
        float b1 = __builtin_inff(), b2v = __builtin_inff();
        unsigned int b1i = 0u, b2i = 0u;
#pragma unroll
        for (int j = 0; j < 4; ++j) {
          const float v = fmaf(-2.f, acc[i][j][r], en4[j]);
          const unsigned int ng = ngb + j * 16;
          if (v < b1) { b2v = b1; b2i = b1i; b1 = v; b1i = ng; }
          else if (v < b2v) { b2v = v; b2i = ng; }
        }
        unsigned long long p1 =
            ((unsigned long long)fmono(b1) << 32) | (unsigned long long)b1i;
        unsigned long long p2 =
            ((unsigned long long)fmono(b2v) << 32) | (unsigned long long)b2i;
        // xor1 merge (lane pairs {0,1},{2,3},... same quad -> same row,
        // disjoint column sets)
        {
          const unsigned long long q1 = shflx(p1, 1);
          const unsigned long long q2 = shflx(p2, 1);
          const unsigned long long hi = umax64(p1, q1);
          p1 = umin64(p1, q1);
          p2 = umin64(hi, umin64(p2, q2));
        }
        if (!(lane & 1)) {
          const int row = mrow + r;
          u64x2 w; w.x = p1; w.y = p2;
          // 16 writers/row across 2 waves -> 16 distinct slots (disjoint
          // halves by wid&1; ^(row&7) touches bits 0-2 only, bijective).
          *(u64x2*)&sh.mg[row][((wid & 1) * 8 + (l15 >> 1)) ^ (row & 7)][0] = w;
        }
      }
    }
    __syncthreads();

    if (tid < BM) {
#pragma unroll
      for (int s = 0; s < 16; ++s) {
        const u64x2 v = *(const u64x2*)&sh.mg[tid][s ^ (tid & 7)][0];
        const unsigned long long v1 = v.x, v2 = v.y;
        const unsigned long long lo = umin64(v1, g1);
        const unsigned long long hi = umax64(v1, g1);
        g1 = lo;
        g2 = umin64(hi, umin64(v2, g2));
      }
    }
    __syncthreads();   // protect mg from next nt's staging into buf
  }

  if (tid < BM) {
    buf1[(size_t)(row0 + tid) * NCHUNK + blockIdx.x] = g1;
    buf2[(size_t)(row0 + tid) * NCHUNK + blockIdx.x] = g2;
  }
}

// ---------------- fused: exact fp64 rerank + gather + loss ----------------
// One wave per token. Butterfly reductions leave results in ALL lanes, so the
// whole wave agrees on the winner and gathers/writes the output row itself.
// Loss: per-token partial (NO global atomics -- 16384 same-address atomicAdds
// serialize through one L2 bank, ~280us).
__global__ __launch_bounds__(256) void rerank_gather_loss_kernel(
    const float* __restrict__ xs, const float* __restrict__ ew,
    const unsigned long long* __restrict__ buf1,
    const unsigned long long* __restrict__ buf2,
    float* __restrict__ out, float* __restrict__ loss_part) {
  const int lane = threadIdx.x & 63;
  const int wv = threadIdx.x >> 6;
  const int tok = blockIdx.x * 4 + wv;
  const unsigned long long p = (lane < 32)
      ? buf1[(size_t)tok * NCHUNK + lane]
      : buf2[(size_t)tok * NCHUNK + (lane - 32)];
  const float S = finv((unsigned int)(p >> 32));
  float m = S;
#pragma unroll
  for (int off = 32; off > 0; off >>= 1) m = fminf(m, __shfl_xor(m, off, 64));
  unsigned long long mask = __ballot(S < m + MU);

  const float4 x0 = *(const float4*)(xs + (size_t)tok * DIM + lane * 8);
  const float4 x1 = *(const float4*)(xs + (size_t)tok * DIM + lane * 8 + 4);
  const double xd[8] = {x0.x, x0.y, x0.z, x0.w, x1.x, x1.y, x1.z, x1.w};

  double best = __builtin_inf();
  unsigned int besti = 0xFFFFFFFFu;
  while (mask) {
    const int src = __ffsll(mask) - 1;
    mask &= mask - 1;
    const unsigned int ci = (unsigned int)__shfl((int)(unsigned int)p, src, 64);
    const float4 e0 = *(const float4*)(ew + (size_t)ci * DIM + lane * 8);
    const float4 e1 = *(const float4*)(ew + (size_t)ci * DIM + lane * 8 + 4);
    const double ed[8] = {e0.x, e0.y, e0.z, e0.w, e1.x, e1.y, e1.z, e1.w};
    double s = 0.0;
#pragma unroll
    for (int k = 0; k < 8; ++k) {
      const double d = xd[k] - ed[k];
      s = fma(d, d, s);
    }
#pragma unroll
    for (int off = 32; off > 0; off >>= 1) s += __shfl_xor(s, off, 64);
    if (s < best || (s == best && ci < besti)) { best = s; besti = ci; }
  }

  // gather winner row + loss partial (all lanes agree on besti)
  const float4 e0 = *(const float4*)(ew + (size_t)besti * DIM + lane * 8);
  const float4 e1 = *(const float4*)(ew + (size_t)besti * DIM + lane * 8 + 4);
  *(float4*)(out + (size_t)tok * DIM + lane * 8) = e0;
  *(float4*)(out + (size_t)tok * DIM + lane * 8 + 4) = e1;
  const float ef[8] = {e0.x, e0.y, e0.z, e0.w, e1.x, e1.y, e1.z, e1.w};
  const float xf[8] = {x0.x, x0.y, x0.z, x0.w, x1.x, x1.y, x1.z, x1.w};
  float ls = 0.f;
#pragma unroll
  for (int k = 0; k < 8; ++k) {
    const float d = ef[k] - xf[k];
    ls = fmaf(d, d, ls);
  }
#pragma unroll
  for (int off = 32; off > 0; off >>= 1) ls += __shfl_xor(ls, off, 64);
  if (lane == 0) loss_part[tok] = ls;
}

// fast-path finalize: tree-reduce 16384 per-token partials, one block.
__global__ __launch_bounds__(256) void loss_reduce_finalize(
    const float* __restrict__ part, float* __restrict__ out, int out_size) {
  const int t = threadIdx.x;
  float s = 0.f;
  for (int i = t; i < N_TOK; i += 256) s += part[i];
#pragma unroll
  for (int off = 32; off > 0; off >>= 1) s += __shfl_down(s, off, 64);
  __shared__ float ws4[4];
  if ((t & 63) == 0) ws4[t >> 6] = s;
  __syncthreads();
  if (t == 0)
    out[out_size - 1] = (ws4[0] + ws4[1] + ws4[2] + ws4[3]) * 1.25f /
                        (float)((size_t)N_TOK * DIM);
}

__global__ void loss_finalize(const float* __restrict__ loss_acc,
                              float* __restrict__ out, int out_size) {
  if (threadIdx.x == 0 && blockIdx.x == 0)
    out[out_size - 1] = *loss_acc * 1.25f / (float)((size_t)N_TOK * DIM);
}

// ---------------- fallback: R5 exact fp64 brute (known-passing) ----------------
#define TT 16
#define CT 16
#define KH 256
#define XPAD 516
#define EPAD 260
__global__ __launch_bounds__(256) void brute_argmin_kernel(
    const float* __restrict__ xs, const float* __restrict__ ew,
    unsigned int* __restrict__ g_idx) {
  __shared__ __align__(16) float Xs[TT * XPAD];
  __shared__ __align__(16) float Es[CT * EPAD];
  __shared__ double cand_v[256];
  __shared__ unsigned int cand_i[256];
  const int t = threadIdx.x;
  const int tok0 = blockIdx.x * TT;
#pragma unroll
  for (int i = 0; i < 32; ++i) {
    const int idx = i * 256 + t;
    const int row = idx >> 9, col = idx & 511;
    Xs[row * XPAD + col] = xs[(size_t)(tok0 + row) * DIM + col];
  }
  const int tt = t >> 4;
  const int cl = t & 15;
  double bv = __builtin_inf();
  unsigned int bi = 0u;
  for (int c0 = 0; c0 < K_CODES; c0 += CT) {
    double s0 = 0.0, s1 = 0.0, s2 = 0.0, s3 = 0.0;
#pragma unroll
    for (int h = 0; h < 2; ++h) {
      __syncthreads();
#pragma unroll
      for (int i = 0; i < 16; ++i) {
        const int idx = i * 256 + t;
        const int row = idx >> 8, col = idx & 255;
        Es[row * EPAD + col] = ew[(size_t)(c0 + row) * DIM + h * KH + col];
      }
      __syncthreads();
      const float* __restrict__ xr = &Xs[tt * XPAD + h * KH];
      const float* __restrict__ er = &Es[cl * EPAD];
#pragma unroll 8
      for (int d = 0; d < KH; d += 4) {
        const float4 xf = *(const float4*)(xr + d);
        const float4 ef = *(const float4*)(er + d);
        const double a0 = (double)xf.x - (double)ef.x;
        const double a1 = (double)xf.y - (double)ef.y;
        const double a2 = (double)xf.z - (double)ef.z;
        const double a3 = (double)xf.w - (double)ef.w;
        s0 = fma(a0, a0, s0); s1 = fma(a1, a1, s1);
        s2 = fma(a2, a2, s2); s3 = fma(a3, a3, s3);
      }
    }
    const double s = (s0 + s1) + (s2 + s3);
    if (s < bv) { bv = s; bi = (unsigned int)(c0 + cl); }
  }
  cand_v[t] = bv; cand_i[t] = bi;
  __syncthreads();
  if (t < TT) {
    double mv = __builtin_inf();
    unsigned int mi = 0xFFFFFFFFu;
#pragma unroll
    for (int j = 0; j < 16; ++j) {
      const double v = cand_v[t * 16 + j];
      const unsigned int i = cand_i[t * 16 + j];
      if (v < mv || (v == mv && i < mi)) { mv = v; mi = i; }
    }
    g_idx[tok0 + t] = mi;
  }
}

__global__ __launch_bounds__(256) void gather_loss_kernel(
    const float* __restrict__ xs, const float* __restrict__ ew,
    const unsigned int* __restrict__ g_idx,
    float* __restrict__ out, float* __restrict__ loss_acc) {
  const int row = blockIdx.x;
  const int t = threadIdx.x;
  const unsigned int idx = g_idx[row];
  const float2 ev = ((const float2*)(ew + (size_t)idx * DIM))[t];
  const float2 xv = ((const float2*)(xs + (size_t)row * DIM))[t];
  ((float2*)(out + (size_t)row * DIM))[t] = ev;
  const float d0 = ev.x - xv.x;
  const float d1 = ev.y - xv.y;
  float s = fmaf(d0, d0, d1 * d1);
#pragma unroll
  for (int off = 32; off > 0; off >>= 1) s += __shfl_down(s, off, 64);
  __shared__ float wsum[4];
  if ((t & 63) == 0) wsum[t >> 6] = s;
  __syncthreads();
  if (t == 0) atomicAdd(loss_acc, wsum[0] + wsum[1] + wsum[2] + wsum[3]);
}

// ---------------- launch ----------------
extern "C" void kernel_launch(void* const* d_in, const int* in_sizes, int n_in,
                              void* d_out, int out_size, void* d_ws, size_t ws_size,
                              hipStream_t stream) {
  const float* xs = (const float*)d_in[0];
  const float* ew = (const float*)d_in[1];
  if (n_in >= 2 && in_sizes[0] == K_CODES * DIM && in_sizes[1] == N_TOK * DIM) {
    const float* tmp = xs; xs = ew; ew = tmp;
  }
  float* out = (float*)d_out;

  char* w = (char*)d_ws;
  _Float16* X16 = (_Float16*)(w);                                   // 16 MB
  _Float16* E16 = (_Float16*)(w + 16777216);                        // 8 MB
  float* enorm = (float*)(w + 25165824);                            // 32 KB
  unsigned long long* buf1 = (unsigned long long*)(w + 25198592);   // 4 MB
  unsigned long long* buf2 = (unsigned long long*)(w + 29392896);   // 4 MB
  const size_t NEED = 33587264;

  // loss partials overlay the X16 region: X16 is dead after the gemm, and
  // rerank (its writer) is stream-ordered after gemm. Zero extra workspace.
  float* loss_part = (float*)(w);

  if (ws_size < NEED) {   // fallback: proven R5 exact path
    unsigned int* fg_idx = (unsigned int*)d_ws;
    float* floss = (float*)((char*)d_ws + (size_t)N_TOK * 4);
    hipMemsetAsync(floss, 0, 4, stream);
    brute_argmin_kernel<<<N_TOK / TT, 256, 0, stream>>>(xs, ew, fg_idx);
    gather_loss_kernel<<<N_TOK, 256, 0, stream>>>(xs, ew, fg_idx, out, floss);
    loss_finalize<<<1, 64, 0, stream>>>(floss, out, out_size);
    return;
  }

  castx_kernel<<<N_TOK * DIM / 4 / 256, 256, 0, stream>>>(xs, X16);
  enorm_cast_kernel<<<K_CODES / 4, 256, 0, stream>>>(ew, enorm, E16);

  dim3 g2(K_CODES / (BN * NT), N_TOK / BM);   // 32 x 128
  gemm_top2_kernel<<<g2, 256, 0, stream>>>(X16, E16, enorm, buf1, buf2);

  rerank_gather_loss_kernel<<<N_TOK / 4, 256, 0, stream>>>(xs, ew, buf1, buf2,
                                                           out, loss_part);
  loss_reduce_finalize<<<1, 256, 0, stream>>>(loss_part, out, out_size);
}

// Round 7
// 317.276 us; speedup vs baseline: 1.9390x; 1.0700x over previous
//
// R7: gemm is LDS-BW-bound (model: 8KB ds-read/wave/k-step for 16 MFMAs ->
// 25% MfmaUtil ceiling == measured). Fold NT into BN: BN=256, wave tile
// 64x128 -> 12KB/32 MFMAs (+37% FLOP per LDS byte), A staged+read once,
// single epilogue pass. Same grid/chunk contract (NCHUNK=32). acc 128 VGPR;
// pre-registered spill signature: FETCH/WRITE jump + SGPR~112 -> revert.
#include <hip/hip_runtime.h>
#include <stdint.h>

#define N_TOK   16384
#define DIM     512
#define K_CODES 8192
#define BM      128
#define BN      256
#define BK      32
#define NCHUNK  32
#define MU      0.25f    // rerank margin; fp16 score err sigma ~0.015

typedef __attribute__((ext_vector_type(8))) _Float16 f16x8;
typedef __attribute__((ext_vector_type(4))) _Float16 f16x4;
typedef __attribute__((ext_vector_type(4))) float f32x4;
typedef __attribute__((ext_vector_type(2))) unsigned long long u64x2;

__device__ __forceinline__ unsigned int fmono(float f) {
  unsigned int b = __float_as_uint(f);
  unsigned int mask = ((int)b < 0) ? 0xFFFFFFFFu : 0x80000000u;
  return b ^ mask;
}
__device__ __forceinline__ float finv(unsigned int m) {
  return (m & 0x80000000u) ? __uint_as_float(m ^ 0x80000000u)
                           : __uint_as_float(~m);
}
__device__ __forceinline__ void async16(const void* gptr, void* lptr) {
  __builtin_amdgcn_global_load_lds(
      (const __attribute__((address_space(1))) unsigned int*)gptr,
      (__attribute__((address_space(3))) unsigned int*)lptr,
      16, 0, 0);
}
__device__ __forceinline__ unsigned long long shflx(unsigned long long v, int x) {
  const int lo = __shfl_xor((int)(unsigned int)v, x, 64);
  const int hi = __shfl_xor((int)(unsigned int)(v >> 32), x, 64);
  return ((unsigned long long)(unsigned int)hi << 32) | (unsigned int)lo;
}
__device__ __forceinline__ unsigned long long umin64(unsigned long long a,
                                                     unsigned long long b) {
  return a < b ? a : b;
}
__device__ __forceinline__ unsigned long long umax64(unsigned long long a,
                                                     unsigned long long b) {
  return a < b ? b : a;
}

// ---------------- cast X: fp32 -> fp16 ----------------
__global__ __launch_bounds__(256) void castx_kernel(
    const float* __restrict__ in, _Float16* __restrict__ out) {
  const int gid = blockIdx.x * 256 + threadIdx.x;   // one float4 each
  const float4 v = ((const float4*)in)[gid];
  f16x4 h;
  h.x = (_Float16)v.x; h.y = (_Float16)v.y;
  h.z = (_Float16)v.z; h.w = (_Float16)v.w;
  *(f16x4*)(out + (size_t)gid * 4) = h;
}

// ---------------- enorm (fp64-exact) + cast E: fp32 -> fp16 ----------------
__global__ __launch_bounds__(256) void enorm_cast_kernel(
    const float* __restrict__ ew, float* __restrict__ enorm,
    _Float16* __restrict__ E16) {
  const int lane = threadIdx.x & 63;
  const int wid  = threadIdx.x >> 6;
  const int row  = blockIdx.x * 4 + wid;
  const float4 v0 = *(const float4*)(ew + (size_t)row * DIM + lane * 8);
  const float4 v1 = *(const float4*)(ew + (size_t)row * DIM + lane * 8 + 4);
  const float f[8] = {v0.x, v0.y, v0.z, v0.w, v1.x, v1.y, v1.z, v1.w};
  f16x8 h;
  double s = 0.0;
#pragma unroll
  for (int k = 0; k < 8; ++k) {
    s = fma((double)f[k], (double)f[k], s);
    h[k] = (_Float16)f[k];
  }
  *(f16x8*)(E16 + (size_t)row * DIM + lane * 8) = h;
#pragma unroll
  for (int off = 32; off > 0; off >>= 1) s += __shfl_down(s, off, 64);
  if (lane == 0) enorm[row] = (float)s;
}

// ---------------- main: fp16 K=512 GEMM + per-chunk top-2 ----------------
// score(i,k) = ||e_k||^2 - 2*x_i.e_k  (fp16 operands, fp32 MFMA accumulate)
// Block tile 128x256 (one full chunk), 4 waves, wave tile 64x128.
// K-loop: 2-phase LDS double-buffer (proven R6): STAGE(next) overlaps
// compute(cur); one __syncthreads() per k-step. Per phase: A 8KB + B 16KB.
// Epilogue (ONCE per block): per-thread top-2 over j=0..7, xor1 shuffle
// merge, even lanes write to 16 slots/row (disjoint wave halves by wid&1,
// ^(row&7) swizzle); scanner merges 16 slots -> buf1/buf2 direct.
// Merge buffer (32KB) aliases buf via union: written only after the final
// k-step barrier; no staging follows (no nt loop) -> no hazard.
__global__ __launch_bounds__(256) void gemm_top2_kernel(
    const _Float16* __restrict__ X16,   // N x 512
    const _Float16* __restrict__ E16,   // K x 512
    const float* __restrict__ enorm,
    unsigned long long* __restrict__ buf1,   // [token][32] packed top-1
    unsigned long long* __restrict__ buf2) { // [token][32] packed top-2
  __shared__ __align__(16) union {
    _Float16 buf[2][12288];           // per phase: A bytes 0..8K, B 8K..24K
    unsigned long long mg[BM][16][2]; // 32KB merge
  } sh;

  const int tid  = threadIdx.x;
  const int lane = tid & 63;
  const int wid  = tid >> 6;
  const int quad = lane >> 4;
  const int l15  = lane & 15;

  const int row0  = blockIdx.y * BM;
  const int nbase = blockIdx.x * BN;

  const int wm = (wid >> 1) * 64;    // 0 or 64  (rows)
  const int wn = (wid & 1) * 128;    // 0 or 128 (codes)

  // staging: 24 issues of 1KB (16 rows x 64B): A issues 0..7, B issues 8..23.
  // wave w handles issues [6w, 6w+6). lane -> row lane>>2, phys slot lane&3,
  // fetched logical chunk (lane&3)^((lane>>3)&3)  (baseline-verified map).
  const int issue0 = wid * 6;
  const int srow   = lane >> 2;
  const int schunk = (lane & 3) ^ ((lane >> 3) & 3);

  auto STAGE = [&](int p, int k0) {
    char* base = (char*)(&sh.buf[p][0]);
#pragma unroll
    for (int q = 0; q < 6; ++q) {
      const int issue = issue0 + q;
      if (issue < 8) {              // A: 128 rows
        const int r = issue * 16 + srow;
        async16(X16 + (size_t)(row0 + r) * DIM + k0 + schunk * 8,
                base + issue * 1024);
      } else {                      // B: 256 codes
        const int bi = issue - 8;
        const int r = bi * 16 + srow;
        async16(E16 + (size_t)(nbase + r) * DIM + k0 + schunk * 8,
                base + 8192 + bi * 1024);
      }
    }
  };

  f32x4 acc[4][8];
#pragma unroll
  for (int i = 0; i < 4; ++i)
#pragma unroll
    for (int j = 0; j < 8; ++j) acc[i][j] = (f32x4){0.f, 0.f, 0.f, 0.f};

  STAGE(0, 0);
  __syncthreads();

  for (int ks = 0; ks < DIM / BK; ++ks) {
    const int p = ks & 1;
    if (ks < DIM / BK - 1) STAGE(p ^ 1, (ks + 1) * BK);

    const char* baseA = (const char*)(&sh.buf[p][0]);
    const char* baseB = baseA + 8192;
    f16x8 a[4];
#pragma unroll
    for (int i = 0; i < 4; ++i) {
      const int ra = wm + i * 16 + l15;
      a[i] = *(const f16x8*)(baseA + ra * 64 + ((quad ^ ((ra >> 1) & 3)) * 16));
    }
    // two j-halves of 4: limits concurrent b-frag liveness to 32 VGPR;
    // each half's ds_reads hide under its 16 MFMAs.
#pragma unroll
    for (int jh = 0; jh < 2; ++jh) {
      f16x8 b[4];
#pragma unroll
      for (int jj = 0; jj < 4; ++jj) {
        const int rb = wn + (jh * 4 + jj) * 16 + l15;
        b[jj] = *(const f16x8*)(baseB + rb * 64 + ((quad ^ ((rb >> 1) & 3)) * 16));
      }
#pragma unroll
      for (int i = 0; i < 4; ++i)
#pragma unroll
        for (int jj = 0; jj < 4; ++jj)
          acc[i][jh * 4 + jj] = __builtin_amdgcn_mfma_f32_16x16x32_f16(
              a[i], b[jj], acc[i][jh * 4 + jj], 0, 0, 0);
    }
    __syncthreads();   // drains this iter's STAGE (vmcnt) + all ds_reads
  }

  // ---- epilogue (atomic-free, single pass) ----
  float en8[8];
#pragma unroll
  for (int j = 0; j < 8; ++j) en8[j] = enorm[nbase + wn + j * 16 + l15];
  const unsigned int ngb = (unsigned int)(nbase + wn + l15);

#pragma unroll
  for (int i = 0; i < 4; ++i) {
    const int mrow = wm + i * 16 + quad * 4;
#pragma unroll
    for (int r = 0; r < 4; ++r) {
      float b1 = __builtin_inff(), b2v = __builtin_inff();
      unsigned int b1i = 0u, b2i = 0u;
#pragma unroll
      for (int j = 0; j < 8; ++j) {
        const float v = fmaf(-2.f, acc[i][j][r], en8[j]);
        const unsigned int ng = ngb + j * 16;
        if (v < b1) { b2v = b1; b2i = b1i; b1 = v; b1i = ng; }
        else if (v < b2v) { b2v = v; b2i = ng; }
      }
      unsigned long long p1 =
          ((unsigned long long)fmono(b1) << 32) | (unsigned long long)b1i;
      unsigned long long p2 =
          ((unsigned long long)fmono(b2v) << 32) | (unsigned long long)b2i;
      // xor1 merge (lane pairs same quad -> same row, disjoint column sets)
      {
        const unsigned long long q1 = shflx(p1, 1);
        const unsigned long long q2 = shflx(p2, 1);
        const unsigned long long hi = umax64(p1, q1);
        p1 = umin64(p1, q1);
        p2 = umin64(hi, umin64(p2, q2));
      }
      if (!(lane & 1)) {
        const int row = mrow + r;
        u64x2 w; w.x = p1; w.y = p2;
        // 16 writers/row across 2 waves -> 16 distinct slots (disjoint
        // halves by wid&1; ^(row&7) touches bits 0-2 only, bijective).
        *(u64x2*)&sh.mg[row][((wid & 1) * 8 + (l15 >> 1)) ^ (row & 7)][0] = w;
      }
    }
  }
  __syncthreads();

  if (tid < BM) {
    unsigned long long g1 = ~0ull, g2 = ~0ull;
#pragma unroll
    for (int s = 0; s < 16; ++s) {
      const u64x2 v = *(const u64x2*)&sh.mg[tid][s ^ (tid & 7)][0];
      const unsigned long long v1 = v.x, v2 = v.y;
      const unsigned long long lo = umin64(v1, g1);
      const unsigned long long hi = umax64(v1, g1);
      g1 = lo;
      g2 = umin64(hi, umin64(v2, g2));
    }
    buf1[(size_t)(row0 + tid) * NCHUNK + blockIdx.x] = g1;
    buf2[(size_t)(row0 + tid) * NCHUNK + blockIdx.x] = g2;
  }
}

// ---------------- fused: exact fp64 rerank + gather + loss ----------------
// One wave per token. Butterfly reductions leave results in ALL lanes, so the
// whole wave agrees on the winner and gathers/writes the output row itself.
// Loss: per-token partial (no global atomics).
__global__ __launch_bounds__(256) void rerank_gather_loss_kernel(
    const float* __restrict__ xs, const float* __restrict__ ew,
    const unsigned long long* __restrict__ buf1,
    const unsigned long long* __restrict__ buf2,
    float* __restrict__ out, float* __restrict__ loss_part) {
  const int lane = threadIdx.x & 63;
  const int wv = threadIdx.x >> 6;
  const int tok = blockIdx.x * 4 + wv;
  const unsigned long long p = (lane < 32)
      ? buf1[(size_t)tok * NCHUNK + lane]
      : buf2[(size_t)tok * NCHUNK + (lane - 32)];
  const float S = finv((unsigned int)(p >> 32));
  float m = S;
#pragma unroll
  for (int off = 32; off > 0; off >>= 1) m = fminf(m, __shfl_xor(m, off, 64));
  unsigned long long mask = __ballot(S < m + MU);

  const float4 x0 = *(const float4*)(xs + (size_t)tok * DIM + lane * 8);
  const float4 x1 = *(const float4*)(xs + (size_t)tok * DIM + lane * 8 + 4);
  const double xd[8] = {x0.x, x0.y, x0.z, x0.w, x1.x, x1.y, x1.z, x1.w};

  double best = __builtin_inf();
  unsigned int besti = 0xFFFFFFFFu;
  while (mask) {
    const int src = __ffsll(mask) - 1;
    mask &= mask - 1;
    const unsigned int ci = (unsigned int)__shfl((int)(unsigned int)p, src, 64);
    const float4 e0 = *(const float4*)(ew + (size_t)ci * DIM + lane * 8);
    const float4 e1 = *(const float4*)(ew + (size_t)ci * DIM + lane * 8 + 4);
    const double ed[8] = {e0.x, e0.y, e0.z, e0.w, e1.x, e1.y, e1.z, e1.w};
    double s = 0.0;
#pragma unroll
    for (int k = 0; k < 8; ++k) {
      const double d = xd[k] - ed[k];
      s = fma(d, d, s);
    }
#pragma unroll
    for (int off = 32; off > 0; off >>= 1) s += __shfl_xor(s, off, 64);
    if (s < best || (s == best && ci < besti)) { best = s; besti = ci; }
  }

  // gather winner row + loss partial (all lanes agree on besti)
  const float4 e0 = *(const float4*)(ew + (size_t)besti * DIM + lane * 8);
  const float4 e1 = *(const float4*)(ew + (size_t)besti * DIM + lane * 8 + 4);
  *(float4*)(out + (size_t)tok * DIM + lane * 8) = e0;
  *(float4*)(out + (size_t)tok * DIM + lane * 8 + 4) = e1;
  const float ef[8] = {e0.x, e0.y, e0.z, e0.w, e1.x, e1.y, e1.z, e1.w};
  const float xf[8] = {x0.x, x0.y, x0.z, x0.w, x1.x, x1.y, x1.z, x1.w};
  float ls = 0.f;
#pragma unroll
  for (int k = 0; k < 8; ++k) {
    const float d = ef[k] - xf[k];
    ls = fmaf(d, d, ls);
  }
#pragma unroll
  for (int off = 32; off > 0; off >>= 1) ls += __shfl_xor(ls, off, 64);
  if (lane == 0) loss_part[tok] = ls;
}

// fast-path finalize: tree-reduce 16384 per-token partials, one block.
__global__ __launch_bounds__(256) void loss_reduce_finalize(
    const float* __restrict__ part, float* __restrict__ out, int out_size) {
  const int t = threadIdx.x;
  float s = 0.f;
  for (int i = t; i < N_TOK; i += 256) s += part[i];
#pragma unroll
  for (int off = 32; off > 0; off >>= 1) s += __shfl_down(s, off, 64);
  __shared__ float ws4[4];
  if ((t & 63) == 0) ws4[t >> 6] = s;
  __syncthreads();
  if (t == 0)
    out[out_size - 1] = (ws4[0] + ws4[1] + ws4[2] + ws4[3]) * 1.25f /
                        (float)((size_t)N_TOK * DIM);
}

__global__ void loss_finalize(const float* __restrict__ loss_acc,
                              float* __restrict__ out, int out_size) {
  if (threadIdx.x == 0 && blockIdx.x == 0)
    out[out_size - 1] = *loss_acc * 1.25f / (float)((size_t)N_TOK * DIM);
}

// ---------------- fallback: R5 exact fp64 brute (known-passing) ----------------
#define TT 16
#define CT 16
#define KH 256
#define XPAD 516
#define EPAD 260
__global__ __launch_bounds__(256) void brute_argmin_kernel(
    const float* __restrict__ xs, const float* __restrict__ ew,
    unsigned int* __restrict__ g_idx) {
  __shared__ __align__(16) float Xs[TT * XPAD];
  __shared__ __align__(16) float Es[CT * EPAD];
  __shared__ double cand_v[256];
  __shared__ unsigned int cand_i[256];
  const int t = threadIdx.x;
  const int tok0 = blockIdx.x * TT;
#pragma unroll
  for (int i = 0; i < 32; ++i) {
    const int idx = i * 256 + t;
    const int row = idx >> 9, col = idx & 511;
    Xs[row * XPAD + col] = xs[(size_t)(tok0 + row) * DIM + col];
  }
  const int tt = t >> 4;
  const int cl = t & 15;
  double bv = __builtin_inf();
  unsigned int bi = 0u;
  for (int c0 = 0; c0 < K_CODES; c0 += CT) {
    double s0 = 0.0, s1 = 0.0, s2 = 0.0, s3 = 0.0;
#pragma unroll
    for (int h = 0; h < 2; ++h) {
      __syncthreads();
#pragma unroll
      for (int i = 0; i < 16; ++i) {
        const int idx = i * 256 + t;
        const int row = idx >> 8, col = idx & 255;
        Es[row * EPAD + col] = ew[(size_t)(c0 + row) * DIM + h * KH + col];
      }
      __syncthreads();
      const float* __restrict__ xr = &Xs[tt * XPAD + h * KH];
      const float* __restrict__ er = &Es[cl * EPAD];
#pragma unroll 8
      for (int d = 0; d < KH; d += 4) {
        const float4 xf = *(const float4*)(xr + d);
        const float4 ef = *(const float4*)(er + d);
        const double a0 = (double)xf.x - (double)ef.x;
        const double a1 = (double)xf.y - (double)ef.y;
        const double a2 = (double)xf.z - (double)ef.z;
        const double a3 = (double)xf.w - (double)ef.w;
        s0 = fma(a0, a0, s0); s1 = fma(a1, a1, s1);
        s2 = fma(a2, a2, s2); s3 = fma(a3, a3, s3);
      }
    }
    const double s = (s0 + s1) + (s2 + s3);
    if (s < bv) { bv = s; bi = (unsigned int)(c0 + cl); }
  }
  cand_v[t] = bv; cand_i[t] = bi;
  __syncthreads();
  if (t < TT) {
    double mv = __builtin_inf();
    unsigned int mi = 0xFFFFFFFFu;
#pragma unroll
    for (int j = 0; j < 16; ++j) {
      const double v = cand_v[t * 16 + j];
      const unsigned int i = cand_i[t * 16 + j];
      if (v < mv || (v == mv && i < mi)) { mv = v; mi = i; }
    }
    g_idx[tok0 + t] = mi;
  }
}

__global__ __launch_bounds__(256) void gather_loss_kernel(
    const float* __restrict__ xs, const float* __restrict__ ew,
    const unsigned int* __restrict__ g_idx,
    float* __restrict__ out, float* __restrict__ loss_acc) {
  const int row = blockIdx.x;
  const int t = threadIdx.x;
  const unsigned int idx = g_idx[row];
  const float2 ev = ((const float2*)(ew + (size_t)idx * DIM))[t];
  const float2 xv = ((const float2*)(xs + (size_t)row * DIM))[t];
  ((float2*)(out + (size_t)row * DIM))[t] = ev;
  const float d0 = ev.x - xv.x;
  const float d1 = ev.y - xv.y;
  float s = fmaf(d0, d0, d1 * d1);
#pragma unroll
  for (int off = 32; off > 0; off >>= 1) s += __shfl_down(s, off, 64);
  __shared__ float wsum[4];
  if ((t & 63) == 0) wsum[t >> 6] = s;
  __syncthreads();
  if (t == 0) atomicAdd(loss_acc, wsum[0] + wsum[1] + wsum[2] + wsum[3]);
}

// ---------------- launch ----------------
extern "C" void kernel_launch(void* const* d_in, const int* in_sizes, int n_in,
                              void* d_out, int out_size, void* d_ws, size_t ws_size,
                              hipStream_t stream) {
  const float* xs = (const float*)d_in[0];
  const float* ew = (const float*)d_in[1];
  if (n_in >= 2 && in_sizes[0] == K_CODES * DIM && in_sizes[1] == N_TOK * DIM) {
    const float* tmp = xs; xs = ew; ew = tmp;
  }
  float* out = (float*)d_out;

  char* w = (char*)d_ws;
  _Float16* X16 = (_Float16*)(w);                                   // 16 MB
  _Float16* E16 = (_Float16*)(w + 16777216);                        // 8 MB
  float* enorm = (float*)(w + 25165824);                            // 32 KB
  unsigned long long* buf1 = (unsigned long long*)(w + 25198592);   // 4 MB
  unsigned long long* buf2 = (unsigned long long*)(w + 29392896);   // 4 MB
  const size_t NEED = 33587264;

  // loss partials overlay the X16 region: X16 is dead after the gemm, and
  // rerank (its writer) is stream-ordered after gemm. Zero extra workspace.
  float* loss_part = (float*)(w);

  if (ws_size < NEED) {   // fallback: proven R5 exact path
    unsigned int* fg_idx = (unsigned int*)d_ws;
    float* floss = (float*)((char*)d_ws + (size_t)N_TOK * 4);
    hipMemsetAsync(floss, 0, 4, stream);
    brute_argmin_kernel<<<N_TOK / TT, 256, 0, stream>>>(xs, ew, fg_idx);
    gather_loss_kernel<<<N_TOK, 256, 0, stream>>>(xs, ew, fg_idx, out, floss);
    loss_finalize<<<1, 64, 0, stream>>>(floss, out, out_size);
    return;
  }

  castx_kernel<<<N_TOK * DIM / 4 / 256, 256, 0, stream>>>(xs, X16);
  enorm_cast_kernel<<<K_CODES / 4, 256, 0, stream>>>(ew, enorm, E16);

  dim3 g2(K_CODES / BN, N_TOK / BM);   // 32 x 128
  gemm_top2_kernel<<<g2, 256, 0, stream>>>(X16, E16, enorm, buf1, buf2);

  rerank_gather_loss_kernel<<<N_TOK / 4, 256, 0, stream>>>(xs, ew, buf1, buf2,
                                                           out, loss_part);
  loss_reduce_finalize<<<1, 256, 0, stream>>>(loss_part, out, out_size);
}